// Round 5
// baseline (359.938 us; speedup 1.0000x reference)
//
#include <hip/hip_runtime.h>
#include <stdint.h>

#define VGRID 16
#define NV 4096            // 16^3 voxels
#define MINPTS 3
#define VEPS 1e-6f

// monotone float<->uint encoding for atomicMin/Max on floats
__device__ __forceinline__ unsigned fenc(float f){
  unsigned b = __float_as_uint(f);
  return (b & 0x80000000u) ? ~b : (b | 0x80000000u);
}
__device__ __forceinline__ float fdec(unsigned u){
  unsigned b = (u & 0x80000000u) ? (u & 0x7FFFFFFFu) : ~u;
  return __uint_as_float(b);
}

// ws layout per chunk: mm (Bc*8 uint) | cnt (Bc*NV int) | s1 (Bc*NV*3 f32) | s2 (Bc*NV*6 f32)
__global__ void k_init(unsigned* mm, int* cnt, float* s1, float* s2, int Bc){
  int stride = gridDim.x * blockDim.x;
  int i0 = blockIdx.x * blockDim.x + threadIdx.x;
  for (int i = i0; i < Bc*8; i += stride) mm[i] = ((i & 7) < 3) ? 0xFFFFFFFFu : 0u;
  int nv = Bc * NV;
  for (int i = i0; i < nv;   i += stride) cnt[i] = 0;
  for (int i = i0; i < nv*3; i += stride) s1[i] = 0.0f;
  for (int i = i0; i < nv*6; i += stride) s2[i] = 0.0f;
}

__global__ __launch_bounds__(256) void k_minmax(const float* __restrict__ pts,
                                                unsigned* __restrict__ mm, int N, int nb, int b0){
  int bl = blockIdx.x / nb, ib = blockIdx.x % nb;
  const float* p = pts + (size_t)(b0 + bl) * N * 3;
  float l0=3e38f,l1=3e38f,l2=3e38f,h0=-3e38f,h1=-3e38f,h2=-3e38f;
  for (int i = ib*256 + (int)threadIdx.x; i < N; i += nb*256){
    size_t o = (size_t)i*3;
    float x = p[o+0], y = p[o+1], z = p[o+2];
    l0=fminf(l0,x); l1=fminf(l1,y); l2=fminf(l2,z);
    h0=fmaxf(h0,x); h1=fmaxf(h1,y); h2=fmaxf(h2,z);
  }
  #pragma unroll
  for (int off=32; off>=1; off>>=1){
    l0=fminf(l0,__shfl_xor(l0,off)); l1=fminf(l1,__shfl_xor(l1,off)); l2=fminf(l2,__shfl_xor(l2,off));
    h0=fmaxf(h0,__shfl_xor(h0,off)); h1=fmaxf(h1,__shfl_xor(h1,off)); h2=fmaxf(h2,__shfl_xor(h2,off));
  }
  __shared__ float red[6][4];
  int wv = threadIdx.x >> 6, ln = threadIdx.x & 63;
  if (ln == 0){ red[0][wv]=l0; red[1][wv]=l1; red[2][wv]=l2; red[3][wv]=h0; red[4][wv]=h1; red[5][wv]=h2; }
  __syncthreads();
  if (threadIdx.x == 0){
    for (int w=1; w<4; w++){
      l0=fminf(l0,red[0][w]); l1=fminf(l1,red[1][w]); l2=fminf(l2,red[2][w]);
      h0=fmaxf(h0,red[3][w]); h1=fmaxf(h1,red[4][w]); h2=fmaxf(h2,red[5][w]);
    }
    atomicMin(&mm[bl*8+0], fenc(l0)); atomicMin(&mm[bl*8+1], fenc(l1)); atomicMin(&mm[bl*8+2], fenc(l2));
    atomicMax(&mm[bl*8+3], fenc(h0)); atomicMax(&mm[bl*8+4], fenc(h1)); atomicMax(&mm[bl*8+5], fenc(h2));
  }
}

// Voxel index, PRECOMPUTED-SCALE f32 semantics (np idiom: scale = GRID/extent, then (p-lo)*scale):
// q = RN32( RN32(p-lo) * RN32(16/ext) )  — double rounding, differs from (p-lo)/ext*16 on ~ulp cases.
__device__ __forceinline__ int vox(float p, float lo, float s){
  float t = p - lo;
  float q = t * s;
  int i = (int)floorf(q);
  return min(max(i, 0), VGRID-1);
}

// PASS 0: cnt + s1(x,y,z)  (LDS 64KB)   PASS 1: s2 xx,xy,xz (48KB)   PASS 2: s2 yy,yz,zz (48KB)
template<int PASS>
__global__ __launch_bounds__(1024) void k_bin(const float* __restrict__ pts,
                                              const unsigned* __restrict__ mm,
                                              int* __restrict__ gcnt, float* __restrict__ gs1,
                                              float* __restrict__ gs2, int N, int nb, int b0){
  int bl = blockIdx.x / nb, ib = blockIdx.x % nb;
  __shared__ float sa[NV], sb[NV], sc[NV];
  __shared__ int   sn[(PASS==0) ? NV : 1];
  for (int v = threadIdx.x; v < NV; v += 1024){
    sa[v]=0.0f; sb[v]=0.0f; sc[v]=0.0f;
    if (PASS==0) sn[v]=0;
  }
  __syncthreads();
  float lo0=fdec(mm[bl*8+0]), lo1=fdec(mm[bl*8+1]), lo2=fdec(mm[bl*8+2]);
  float e0=fmaxf(fdec(mm[bl*8+3])-lo0, VEPS);
  float e1=fmaxf(fdec(mm[bl*8+4])-lo1, VEPS);
  float e2=fmaxf(fdec(mm[bl*8+5])-lo2, VEPS);
  float sc0 = 16.0f / e0;   // correctly-rounded f32 divide, uniform per block
  float sc1 = 16.0f / e1;
  float sc2 = 16.0f / e2;
  const float* p = pts + (size_t)(b0 + bl) * N * 3;
  for (int i = ib*1024 + (int)threadIdx.x; i < N; i += nb*1024){
    size_t o = (size_t)i*3;
    float x = p[o+0], y = p[o+1], z = p[o+2];
    int vid = (vox(x,lo0,sc0)*VGRID + vox(y,lo1,sc1))*VGRID + vox(z,lo2,sc2);
    if (PASS==0){
      atomicAdd(&sn[vid], 1);
      atomicAdd(&sa[vid], x); atomicAdd(&sb[vid], y); atomicAdd(&sc[vid], z);
    } else if (PASS==1){
      atomicAdd(&sa[vid], x*x); atomicAdd(&sb[vid], x*y); atomicAdd(&sc[vid], x*z);
    } else {
      atomicAdd(&sa[vid], y*y); atomicAdd(&sb[vid], y*z); atomicAdd(&sc[vid], z*z);
    }
  }
  __syncthreads();
  for (int v = threadIdx.x; v < NV; v += 1024){
    size_t g = (size_t)bl*NV + v;
    if (PASS==0){
      int c = sn[v];
      if (c){
        atomicAdd(&gcnt[g], c);
        atomicAdd(&gs1[g*3+0], sa[v]); atomicAdd(&gs1[g*3+1], sb[v]); atomicAdd(&gs1[g*3+2], sc[v]);
      }
    } else if (PASS==1){
      if (sa[v] != 0.0f){  // xx==0 => all x==0 => xy==xz==0; skipping exact zeros is a no-op
        atomicAdd(&gs2[g*6+0], sa[v]); atomicAdd(&gs2[g*6+1], sb[v]); atomicAdd(&gs2[g*6+2], sc[v]);
      }
    } else {
      if (sa[v] != 0.0f || sc[v] != 0.0f){ // yy==0 && zz==0 => all y,z==0 => yz==0
        atomicAdd(&gs2[g*6+3], sa[v]); atomicAdd(&gs2[g*6+4], sb[v]); atomicAdd(&gs2[g*6+5], sc[v]);
      }
    }
  }
}

// rank voxels by key desc; tie order = STABLE INDEX-ASC (jax top_k / stable argsort of -score):
// key = (cnt<<12) | (NV-1-v) for valid, (NV-1-v) for invalid. rank<K writes its slot.
__global__ __launch_bounds__(256) void k_select(const int* __restrict__ gcnt,
                                                const float* __restrict__ gs1,
                                                const float* __restrict__ gs2,
                                                float* __restrict__ out, int Btot, int K, int b0){
  const int CPB = NV/256;
  int bl = blockIdx.x / CPB;
  int bg = b0 + bl;
  __shared__ unsigned keys[NV];
  for (int v = threadIdx.x; v < NV; v += 256){
    int c = gcnt[(size_t)bl*NV + v];
    unsigned tiebk = (unsigned)(NV-1-v);
    keys[v] = (c >= MINPTS) ? (((unsigned)c << 12) | tiebk) : tiebk;
  }
  __syncthreads();
  int v = (blockIdx.x % CPB)*256 + (int)threadIdx.x;
  unsigned mykey = keys[v];
  int rank = 0;
  #pragma unroll 4
  for (int j = 0; j < NV; j++) rank += (keys[j] > mykey) ? 1 : 0;
  if (rank >= K) return;
  size_t g = (size_t)bl*NV + v;
  int c = gcnt[g];
  bool valid = (c >= MINPTS);
  float denom = fmaxf((float)c, 1.0f);
  float m0 = gs1[g*3+0]/denom, m1 = gs1[g*3+1]/denom, m2 = gs1[g*3+2]/denom;
  float cxx = gs2[g*6+0]/denom - m0*m0;
  float cxy = gs2[g*6+1]/denom - m0*m1;
  float cxz = gs2[g*6+2]/denom - m0*m2;
  float cyy = gs2[g*6+3]/denom - m1*m1;
  float cyz = gs2[g*6+4]/denom - m1*m2;
  float czz = gs2[g*6+5]/denom - m2*m2;
  if (!valid){ m0=m1=m2=0.0f; cxx=cxy=cxz=cyy=cyz=czz=0.0f; }
  size_t mb = ((size_t)bg*K + rank)*3;
  out[mb+0]=m0; out[mb+1]=m1; out[mb+2]=m2;
  size_t cb = (size_t)Btot*K*3 + ((size_t)bg*K + rank)*9;
  out[cb+0]=cxx; out[cb+1]=cxy; out[cb+2]=cxz;
  out[cb+3]=cxy; out[cb+4]=cyy; out[cb+5]=cyz;
  out[cb+6]=cxz; out[cb+7]=cyz; out[cb+8]=czz;
}

extern "C" void kernel_launch(void* const* d_in, const int* in_sizes, int n_in,
                              void* d_out, int out_size, void* d_ws, size_t ws_size,
                              hipStream_t stream) {
  const float* pts = (const float*)d_in[0];
  const int B = 8;                              // setup_inputs: (8, 500000, 3)
  const int N = in_sizes[0] / (B * 3);
  const int K = out_size / (B * 12);            // 3 (mean) + 9 (cov) floats per dist
  float* out = (float*)d_out;

  // batches per chunk limited by ws_size (40 B per voxel per batch + 1KB header)
  size_t per_b = (size_t)NV * 40;
  int NB = (ws_size > 1024) ? (int)((ws_size - 1024) / per_b) : 1;
  if (NB < 1) NB = 1;
  if (NB > B) NB = B;

  char* ws = (char*)d_ws;
  for (int b0 = 0; b0 < B; b0 += NB){
    int Bc = (B - b0 < NB) ? (B - b0) : NB;
    unsigned* mm  = (unsigned*)ws;
    int*      cnt = (int*)(ws + 1024);
    float*    s1  = (float*)(ws + 1024 + (size_t)Bc*NV*4);
    float*    s2  = (float*)(ws + 1024 + (size_t)Bc*NV*16);

    k_init<<<512, 256, 0, stream>>>(mm, cnt, s1, s2, Bc);

    const int nbm = 128;
    k_minmax<<<Bc*nbm, 256, 0, stream>>>(pts, mm, N, nbm, b0);

    const int nb = 32;
    k_bin<0><<<Bc*nb, 1024, 0, stream>>>(pts, mm, cnt, s1, s2, N, nb, b0);
    k_bin<1><<<Bc*nb, 1024, 0, stream>>>(pts, mm, cnt, s1, s2, N, nb, b0);
    k_bin<2><<<Bc*nb, 1024, 0, stream>>>(pts, mm, cnt, s1, s2, N, nb, b0);

    k_select<<<Bc*(NV/256), 256, 0, stream>>>(cnt, s1, s2, out, B, K, b0);
  }
}